// Round 6
// baseline (580.462 us; speedup 1.0000x reference)
//
#include <hip/hip_runtime.h>
#include <stdint.h>

// Problem constants
#define BB 8
#define SS 2048
#define FF 512
#define HH 4
#define TOK (BB * SS)   // 16384

typedef unsigned short u16;
typedef short short8 __attribute__((ext_vector_type(8)));
typedef float f32x4 __attribute__((ext_vector_type(4)));
typedef float f32x16 __attribute__((ext_vector_type(16)));
typedef unsigned int u32x4 __attribute__((ext_vector_type(4)));

static __device__ __forceinline__ u16 f2bf(float f) {
  uint32_t u = __builtin_bit_cast(uint32_t, f);
  u = (u + 0x7fffu + ((u >> 16) & 1u)) >> 16;
  return (u16)u;
}

// packed f32x2 -> bf16x2 (RNE) in one instruction
static __device__ __forceinline__ uint32_t cvtpk(float lo, float hi) {
  uint32_t r;
  asm("v_cvt_pk_bf16_f32 %0, %1, %2" : "=v"(r) : "v"(lo), "v"(hi));
  return r;
}

// async global->LDS, 16B per lane. LDS dest = wave-uniform base + lane*16.
static __device__ __forceinline__ void cp16(void* lds, const void* g) {
  __builtin_amdgcn_global_load_lds(
      (const __attribute__((address_space(1))) void*)g,
      (__attribute__((address_space(3))) void*)lds, 16, 0, 0);
}

// ---------------------------------------------------------------- cast
__global__ __launch_bounds__(256) void castk(const float* __restrict__ s,
                                             u16* __restrict__ d, int n) {
  const int i = (blockIdx.x * 256 + threadIdx.x) * 8;
  if (i >= n) return;
  float4 a = *(const float4*)(s + i);
  float4 b = *(const float4*)(s + i + 4);
  short8 o;
  o[0] = (short)f2bf(a.x); o[1] = (short)f2bf(a.y);
  o[2] = (short)f2bf(a.z); o[3] = (short)f2bf(a.w);
  o[4] = (short)f2bf(b.x); o[5] = (short)f2bf(b.y);
  o[6] = (short)f2bf(b.z); o[7] = (short)f2bf(b.w);
  *(short8*)(d + i) = o;
}

// ---------------------------------------------------------------- GEMM
// C[M,N] = A[M,K](bf16) * B[N,K]^T(bf16) + bias.  128x128 tile, BK=64,
// 4 waves (2x2, 64x64 each), global_load_lds staging w/ XOR slot swizzle.
// Columns gn < qcols get scaled by qscale (used to pre-scale Q by log2e/sqrt(d)).
__global__ __launch_bounds__(256) void gemm_bt(
    const u16* __restrict__ A, const u16* __restrict__ B,
    const float* __restrict__ bias, float* __restrict__ Cf,
    u16* __restrict__ Cb, int M, int N, int K, int qcols, float qscale) {
  const int m0 = blockIdx.x << 7;
  const int n0 = blockIdx.y << 7;
  __shared__ u16 As[128 * 64];
  __shared__ u16 Bs[128 * 64];
  const int tid = threadIdx.x;
  const int wave = tid >> 6, lane = tid & 63;
  const int wr = wave >> 1, wc = wave & 1;

  f32x4 acc[4][4];
#pragma unroll
  for (int i = 0; i < 4; ++i)
#pragma unroll
    for (int j = 0; j < 4; ++j)
#pragma unroll
      for (int e = 0; e < 4; ++e) acc[i][j][e] = 0.f;

  for (int k0 = 0; k0 < K; k0 += 64) {
#pragma unroll
    for (int i = 0; i < 4; ++i) {
      const int base = (i * 4 + wave) << 10;       // wave-uniform LDS byte base
      const int lb = base + (lane << 4);
      const int r = lb >> 7;                       // row (128B rows)
      const int s = ((lb >> 4) & 7) ^ (r & 7);     // logical 16B slot
      cp16((char*)As + base, A + (size_t)(m0 + r) * K + k0 + s * 8);
      cp16((char*)Bs + base, B + (size_t)(n0 + r) * K + k0 + s * 8);
    }
    __syncthreads();
#pragma unroll
    for (int kk = 0; kk < 2; ++kk) {
      short8 af[4], bfr[4];
#pragma unroll
      for (int mi = 0; mi < 4; ++mi) {
        const int r = wr * 64 + mi * 16 + (lane & 15);
        const int p = (kk * 4 + (lane >> 4)) ^ (r & 7);
        af[mi] = *(const short8*)(As + r * 64 + p * 8);
      }
#pragma unroll
      for (int ni = 0; ni < 4; ++ni) {
        const int r = wc * 64 + ni * 16 + (lane & 15);
        const int p = (kk * 4 + (lane >> 4)) ^ (r & 7);
        bfr[ni] = *(const short8*)(Bs + r * 64 + p * 8);
      }
#pragma unroll
      for (int mi = 0; mi < 4; ++mi)
#pragma unroll
        for (int ni = 0; ni < 4; ++ni)
          acc[mi][ni] = __builtin_amdgcn_mfma_f32_16x16x32_bf16(
              af[mi], bfr[ni], acc[mi][ni], 0, 0, 0);
    }
    __syncthreads();
  }
  const int rv = (lane >> 4) << 2;
  const int cn = lane & 15;
#pragma unroll
  for (int mi = 0; mi < 4; ++mi)
#pragma unroll
    for (int ni = 0; ni < 4; ++ni) {
      const int gn = n0 + wc * 64 + ni * 16 + cn;
      const float bv = bias ? bias[gn] : 0.f;
      const float sc = (gn < qcols) ? qscale : 1.f;
#pragma unroll
      for (int v = 0; v < 4; ++v) {
        const int gm = m0 + wr * 64 + mi * 16 + rv + v;
        const size_t off = (size_t)gm * N + gn;
        const float val = (acc[mi][ni][v] + bv) * sc;
        if (Cf) Cf[off] = val;
        if (Cb) Cb[off] = f2bf(val);
      }
    }
}

// -------------------------------------------------- V transpose (per b,h)
// vt[bh][d][s] = qkv[(b*S+s)*1536 + 1024 + h*128 + d]
__global__ __launch_bounds__(256) void transpose_v(
    const u16* __restrict__ qkv, u16* __restrict__ vt) {
  const int bh = blockIdx.x, st = blockIdx.y, dt = blockIdx.z;
  const int b = bh >> 2, h = bh & 3;
  __shared__ u16 t[64][72];
  const int r = threadIdx.x >> 3;          // 0..31
  const int c8 = (threadIdx.x & 7) * 8;
#pragma unroll
  for (int ph = 0; ph < 2; ++ph) {
    const int srow = ph * 32 + r;
    const u16* src = qkv + (size_t)(b * SS + st * 64 + srow) * 1536 + 1024 +
                     h * 128 + dt * 64 + c8;
    *(short8*)&t[srow][c8] = *(const short8*)src;
  }
  __syncthreads();
#pragma unroll
  for (int ph = 0; ph < 2; ++ph) {
    const int drow = ph * 32 + r;
    short8 o;
#pragma unroll
    for (int j = 0; j < 8; ++j) o[j] = (short)t[c8 + j][drow];
    *(short8*)(vt + ((size_t)bh * 128 + dt * 64 + drow) * SS + st * 64 + c8) = o;
  }
}

// In-register P redistribution (T12): from swapped-QK score regs to PV
// A-fragment. For k-slice ks: block c0=(2ks)&3 serves dest half 0, c0+1 serves
// dest half 1; one permlane32_swap yields both output words.
template <typename GET>
static __device__ __forceinline__ short8 make_pa(int ks, GET get) {
  const int c0 = (2 * ks) & 3;
  u32x4 pw;
#pragma unroll
  for (int t = 0; t < 2; ++t) {
    uint32_t a = cvtpk(get(4 * c0 + 2 * t), get(4 * c0 + 2 * t + 1));
    uint32_t b = cvtpk(get(4 * (c0 + 1) + 2 * t), get(4 * (c0 + 1) + 2 * t + 1));
    auto r = __builtin_amdgcn_permlane32_swap(a, b, false, false);
    pw[t] = r[0];        // j = 2t, 2t+1
    pw[2 + t] = r[1];    // j = 4+2t, 5+2t
  }
  return __builtin_bit_cast(short8, pw);
}

// ---------------------------------------------------------- local attention
// one wave per (b, window, head); 32x32 scores, swapped QK^T, in-reg P (no LDS).
__global__ __launch_bounds__(256) void attn_local(
    const u16* __restrict__ qkv, const u16* __restrict__ vt,
    u16* __restrict__ ao) {
  const int wave = threadIdx.x >> 6, lane = threadIdx.x & 63;
  const int u = blockIdx.x * 4 + wave;
  const int b = u >> 8, w = (u >> 2) & 63, h = u & 3;
  const int q = lane & 31, half = lane >> 5;

  const size_t qbase = (size_t)(b * SS + w * 32 + q) * 1536 + h * 128;
  short8 qf[8];
#pragma unroll
  for (int d8 = 0; d8 < 8; ++d8)
    qf[d8] = *(const short8*)(qkv + qbase + d8 * 16 + half * 8);

  f32x16 s;
#pragma unroll
  for (int e = 0; e < 16; ++e) s[e] = 0.f;
  const size_t kbase = qbase + 512;
#pragma unroll
  for (int d8 = 0; d8 < 8; ++d8) {
    short8 kf = *(const short8*)(qkv + kbase + d8 * 16 + half * 8);
    s = __builtin_amdgcn_mfma_f32_32x32x16_bf16(kf, qf[d8], s, 0, 0, 0);
  }
  // Q pre-scaled by log2e/sqrt(128) in GEMM epilogue -> scores already in log2 domain
  float m = s[0];
#pragma unroll
  for (int e = 1; e < 16; ++e) m = fmaxf(m, s[e]);
  m = fmaxf(m, __shfl_xor(m, 32));
  float l = 0.f;
#pragma unroll
  for (int e = 0; e < 16; ++e) { s[e] = exp2f(s[e] - m); l += s[e]; }
  l += __shfl_xor(l, 32);

  f32x16 o[4];
#pragma unroll
  for (int nt = 0; nt < 4; ++nt)
#pragma unroll
    for (int e = 0; e < 16; ++e) o[nt][e] = 0.f;
  const size_t vbase = ((size_t)(b * 4 + h) * 128) * SS + w * 32;
#pragma unroll
  for (int ks = 0; ks < 2; ++ks) {
    short8 pa = make_pa(ks, [&](int e) { return s[e]; });
#pragma unroll
    for (int nt = 0; nt < 4; ++nt) {
      short8 vb = *(const short8*)(vt + vbase + (size_t)(nt * 32 + q) * SS +
                                   ks * 16 + half * 8);
      o[nt] = __builtin_amdgcn_mfma_f32_32x32x16_bf16(pa, vb, o[nt], 0, 0, 0);
    }
  }
  const float rl = 1.f / l;
  const size_t ob = (size_t)(b * SS + w * 32) * FF + h * 128;
#pragma unroll
  for (int e = 0; e < 16; ++e) {
    const int qr = (e & 3) + 8 * (e >> 2) + 4 * half;
    const float rf = __shfl(rl, qr);
#pragma unroll
    for (int nt = 0; nt < 4; ++nt)
      ao[ob + (size_t)qr * FF + nt * 32 + q] = f2bf(o[nt][e] * rf);
  }
}

// --------------------------------------------------------- global attention
// Zero-LDS / zero-barrier flash attention: K and V^T fragments read DIRECTLY
// from L2 (per-XCD working set = 4 bh-pairs x 1MB = 4MB = L2 size; staging
// them through LDS was pure overhead + barrier lockstep at 2 waves/SIMD).
// block = (b,h,qtile128), 4 waves x 32 q-rows; ktile=64; waves free-run.
__global__ __launch_bounds__(256, 2) void attn_global(
    const u16* __restrict__ qkv, const u16* __restrict__ vtp,
    u16* __restrict__ ao) {
  // XCD swizzle: 512 blocks, 64 consecutive logical blocks (4 bh pairs) per XCD
  const int lb = (blockIdx.x & 7) * 64 + (blockIdx.x >> 3);
  const int bh = lb >> 4, qt = lb & 15;
  const int b = bh >> 2, h = bh & 3;
  const int wave = threadIdx.x >> 6, lane = threadIdx.x & 63;
  const int q = lane & 31, half = lane >> 5;

  short8 qf[8];
  const size_t qb = (size_t)(b * SS + qt * 128 + wave * 32 + q) * 1536 + h * 128;
#pragma unroll
  for (int d8 = 0; d8 < 8; ++d8)
    qf[d8] = *(const short8*)(qkv + qb + d8 * 16 + half * 8);

  f32x16 o[4];
#pragma unroll
  for (int nt = 0; nt < 4; ++nt)
#pragma unroll
    for (int e = 0; e < 16; ++e) o[nt][e] = 0.f;
  float m = -3e38f, lsum = 0.f;

  // per-lane K pointers (row = kt*64 + mt*32 + q of this b's K, head h);
  // d8 offsets (<=224 elems) fold into the load's immediate.
  const u16* pk0 = qkv + (size_t)b * SS * 1536 + 512 + (size_t)h * 128 +
                   (size_t)q * 1536 + half * 8;
  const u16* pk1 = pk0 + (size_t)32 * 1536;
  // per-lane V^T pointers: row d = nt*32+q, col = kt*64 + ks*16 + half*8
  const u16* pvb = vtp + (size_t)bh * 128 * SS + (size_t)q * SS + half * 8;
  const u16* pv0 = pvb;
  const u16* pv1 = pvb + (size_t)32 * SS;
  const u16* pv2 = pvb + (size_t)64 * SS;
  const u16* pv3 = pvb + (size_t)96 * SS;

  for (int kt = 0; kt < 32; ++kt) {
    f32x16 sa[2];
#pragma unroll
    for (int mt = 0; mt < 2; ++mt)
#pragma unroll
      for (int e = 0; e < 16; ++e) sa[mt][e] = 0.f;
#pragma unroll
    for (int d8 = 0; d8 < 8; ++d8) {
      short8 kf0 = *(const short8*)(pk0 + d8 * 16);
      sa[0] = __builtin_amdgcn_mfma_f32_32x32x16_bf16(kf0, qf[d8], sa[0], 0, 0, 0);
    }
#pragma unroll
    for (int d8 = 0; d8 < 8; ++d8) {
      short8 kf1 = *(const short8*)(pk1 + d8 * 16);
      sa[1] = __builtin_amdgcn_mfma_f32_32x32x16_bf16(kf1, qf[d8], sa[1], 0, 0, 0);
    }
    // ---- online softmax, log2 domain (Q pre-scaled), defer-max THR=8
    // tree reductions (depth 5) instead of 31-deep serial chains
    float t[16];
#pragma unroll
    for (int e = 0; e < 16; ++e) t[e] = fmaxf(sa[0][e], sa[1][e]);
#pragma unroll
    for (int st = 8; st >= 1; st >>= 1)
#pragma unroll
      for (int e = 0; e < 8; ++e)
        if (e < st) t[e] = fmaxf(t[e], t[e + st]);
    float pmax = fmaxf(t[0], __shfl_xor(t[0], 32));
    if (__any(pmax > m + 8.f)) {
      const float mn = fmaxf(m, pmax);
      const float corr = exp2f(m - mn);
      m = mn;
      lsum *= corr;
#pragma unroll
      for (int e = 0; e < 16; ++e) {
        const float cf = __shfl(corr, (e & 3) + 8 * (e >> 2) + 4 * half);
#pragma unroll
        for (int nt = 0; nt < 4; ++nt) o[nt][e] *= cf;
      }
    }
#pragma unroll
    for (int mt = 0; mt < 2; ++mt)
#pragma unroll
      for (int e = 0; e < 16; ++e) sa[mt][e] = exp2f(sa[mt][e] - m);
    float u[16];
#pragma unroll
    for (int e = 0; e < 16; ++e) u[e] = sa[0][e] + sa[1][e];
#pragma unroll
    for (int st = 8; st >= 1; st >>= 1)
#pragma unroll
      for (int e = 0; e < 8; ++e)
        if (e < st) u[e] += u[e + st];
    lsum += u[0] + __shfl_xor(u[0], 32);
    // ---- P -> PV A-fragments in-register; PV with V^T direct from L2
#pragma unroll
    for (int ks = 0; ks < 4; ++ks) {
      const int mt = ks >> 1;
      short8 pa = make_pa(ks, [&](int e) { return sa[mt][e]; });
      short8 vb0 = *(const short8*)(pv0 + ks * 16);
      short8 vb1 = *(const short8*)(pv1 + ks * 16);
      short8 vb2 = *(const short8*)(pv2 + ks * 16);
      short8 vb3 = *(const short8*)(pv3 + ks * 16);
      o[0] = __builtin_amdgcn_mfma_f32_32x32x16_bf16(pa, vb0, o[0], 0, 0, 0);
      o[1] = __builtin_amdgcn_mfma_f32_32x32x16_bf16(pa, vb1, o[1], 0, 0, 0);
      o[2] = __builtin_amdgcn_mfma_f32_32x32x16_bf16(pa, vb2, o[2], 0, 0, 0);
      o[3] = __builtin_amdgcn_mfma_f32_32x32x16_bf16(pa, vb3, o[3], 0, 0, 0);
    }
    pk0 += (size_t)64 * 1536;
    pk1 += (size_t)64 * 1536;
    pv0 += 64; pv1 += 64; pv2 += 64; pv3 += 64;
  }
  const float rl = 1.f / lsum;
  const size_t ob = (size_t)(b * SS + qt * 128 + wave * 32) * FF + h * 128;
#pragma unroll
  for (int e = 0; e < 16; ++e) {
    const int qr = (e & 3) + 8 * (e >> 2) + 4 * half;
    const float rf = __shfl(rl, qr);
#pragma unroll
    for (int nt = 0; nt < 4; ++nt)
      ao[ob + (size_t)qr * FF + nt * 32 + q] = f2bf(o[nt][e] * rf);
  }
}

// --------------------------------------------- residual + LayerNorm (in place)
__global__ __launch_bounds__(256) void resid_ln(
    float* __restrict__ y, const float* __restrict__ x,
    const float* __restrict__ w, const float* __restrict__ bv_,
    u16* __restrict__ lg) {
  const int wave = threadIdx.x >> 6, lane = threadIdx.x & 63;
  const size_t row = (size_t)blockIdx.x * 4 + wave;
  const int c = lane * 8;
  float* yr = y + row * FF;
  const float* xr = x + row * FF;
  float v[8];
  {
    float4 a0 = *(const float4*)(yr + c), a1 = *(const float4*)(yr + c + 4);
    float4 b0 = *(const float4*)(xr + c), b1 = *(const float4*)(xr + c + 4);
    v[0] = a0.x + b0.x; v[1] = a0.y + b0.y; v[2] = a0.z + b0.z; v[3] = a0.w + b0.w;
    v[4] = a1.x + b1.x; v[5] = a1.y + b1.y; v[6] = a1.z + b1.z; v[7] = a1.w + b1.w;
  }
  float s = 0.f, s2 = 0.f;
#pragma unroll
  for (int e = 0; e < 8; ++e) { s += v[e]; s2 += v[e] * v[e]; }
#pragma unroll
  for (int off = 1; off < 64; off <<= 1) {
    s += __shfl_xor(s, off);
    s2 += __shfl_xor(s2, off);
  }
  const float mu = s * (1.f / 512.f);
  const float var = s2 * (1.f / 512.f) - mu * mu;
  const float rs = rsqrtf(var + 1e-5f);
  float4 w0 = *(const float4*)(w + c), w1 = *(const float4*)(w + c + 4);
  float4 b0 = *(const float4*)(bv_ + c), b1 = *(const float4*)(bv_ + c + 4);
  const float wv[8] = {w0.x, w0.y, w0.z, w0.w, w1.x, w1.y, w1.z, w1.w};
  const float bb[8] = {b0.x, b0.y, b0.z, b0.w, b1.x, b1.y, b1.z, b1.w};
  short8 ob;
#pragma unroll
  for (int e = 0; e < 8; ++e) {
    v[e] = (v[e] - mu) * rs * wv[e] + bb[e];
    ob[e] = (short)f2bf(v[e]);
  }
  *(float4*)(yr + c) = make_float4(v[0], v[1], v[2], v[3]);
  *(float4*)(yr + c + 4) = make_float4(v[4], v[5], v[6], v[7]);
  *(short8*)(lg + row * 1024 + c) = ob;
}

// ----------------------------------------------- gate LN + sigmoid + mix
__global__ __launch_bounds__(256) void gate_final(
    const float* __restrict__ gp, const float* __restrict__ loc,
    const float* __restrict__ glo, const float* __restrict__ w,
    const float* __restrict__ bv_, float* __restrict__ out) {
  const int wave = threadIdx.x >> 6, lane = threadIdx.x & 63;
  const size_t row = (size_t)blockIdx.x * 4 + wave;
  const int c = lane * 8;
  const float* gr = gp + row * FF;
  float v[8];
  {
    float4 a0 = *(const float4*)(gr + c), a1 = *(const float4*)(gr + c + 4);
    v[0] = a0.x; v[1] = a0.y; v[2] = a0.z; v[3] = a0.w;
    v[4] = a1.x; v[5] = a1.y; v[6] = a1.z; v[7] = a1.w;
  }
  float s = 0.f, s2 = 0.f;
#pragma unroll
  for (int e = 0; e < 8; ++e) { s += v[e]; s2 += v[e] * v[e]; }
#pragma unroll
  for (int off = 1; off < 64; off <<= 1) {
    s += __shfl_xor(s, off);
    s2 += __shfl_xor(s2, off);
  }
  const float mu = s * (1.f / 512.f);
  const float var = s2 * (1.f / 512.f) - mu * mu;
  const float rs = rsqrtf(var + 1e-5f);
  float4 w0 = *(const float4*)(w + c), w1 = *(const float4*)(w + c + 4);
  float4 b0 = *(const float4*)(bv_ + c), b1 = *(const float4*)(bv_ + c + 4);
  const float wv[8] = {w0.x, w0.y, w0.z, w0.w, w1.x, w1.y, w1.z, w1.w};
  const float bb[8] = {b0.x, b0.y, b0.z, b0.w, b1.x, b1.y, b1.z, b1.w};
  float4 l0 = *(const float4*)(loc + row * FF + c), l1 = *(const float4*)(loc + row * FF + c + 4);
  float4 g0 = *(const float4*)(glo + row * FF + c), g1 = *(const float4*)(glo + row * FF + c + 4);
  const float lv[8] = {l0.x, l0.y, l0.z, l0.w, l1.x, l1.y, l1.z, l1.w};
  const float gv[8] = {g0.x, g0.y, g0.z, g0.w, g1.x, g1.y, g1.z, g1.w};
  float r[8];
#pragma unroll
  for (int e = 0; e < 8; ++e) {
    const float z = (v[e] - mu) * rs * wv[e] + bb[e];
    const float gt = 1.f / (1.f + exp2f(-1.44269504f * z));
    r[e] = gt * lv[e] + (1.f - gt) * gv[e];
  }
  *(float4*)(out + row * FF + c) = make_float4(r[0], r[1], r[2], r[3]);
  *(float4*)(out + row * FF + c + 4) = make_float4(r[4], r[5], r[6], r[7]);
}

// ---------------------------------------------------------------- launch
extern "C" void kernel_launch(void* const* d_in, const int* in_sizes, int n_in,
                              void* d_out, int out_size, void* d_ws,
                              size_t ws_size, hipStream_t stream) {
  const float* x       = (const float*)d_in[0];
  const float* l_in_w  = (const float*)d_in[1];
  const float* l_in_b  = (const float*)d_in[2];
  const float* l_out_w = (const float*)d_in[3];
  const float* l_out_b = (const float*)d_in[4];
  const float* g_in_w  = (const float*)d_in[5];
  const float* g_in_b  = (const float*)d_in[6];
  const float* g_out_w = (const float*)d_in[7];
  const float* g_out_b = (const float*)d_in[8];
  const float* n1_w    = (const float*)d_in[9];
  const float* n1_b    = (const float*)d_in[10];
  const float* n2_w    = (const float*)d_in[11];
  const float* n2_b    = (const float*)d_in[12];
  const float* gate_w  = (const float*)d_in[13];
  const float* gate_b  = (const float*)d_in[14];
  const float* gln_w   = (const float*)d_in[15];
  const float* gln_b   = (const float*)d_in[16];
  float* out = (float*)d_out;

  const float c1 = 0.12752724808f;  // log2(e)/sqrt(128)

  char* ws = (char*)d_ws;                       // needs ~207 MB
  u16* x_bf  = (u16*)(ws);                      // 16,777,216
  u16* w_liw = (u16*)(ws + 16777216);           //  1,572,864
  u16* w_giw = (u16*)(ws + 18350080);           //  1,572,864
  u16* w_low = (u16*)(ws + 19922944);           //    524,288
  u16* w_gow = (u16*)(ws + 20447232);           //    524,288
  u16* w_gt  = (u16*)(ws + 20971520);           //  1,048,576
  u16* qkv   = (u16*)(ws + 22020096);           // 50,331,648 (reused per branch)
  u16* vt    = (u16*)(ws + 72351744);           // 16,777,216 (reused)
  u16* ato   = (u16*)(ws + 89128960);           // 16,777,216 (reused)
  float* locf = (float*)(ws + 105906176);       // 33,554,432
  float* glof = (float*)(ws + 139460608);       // 33,554,432
  u16* lgbf  = (u16*)(ws + 173015040);          // 33,554,432  [local|glob] bf16
  float* gpre = (float*)(ws + 22020096);        // alias qkv (free by then)

  castk<<<4096, 256, 0, stream>>>(x, x_bf, 8388608);
  castk<<<384, 256, 0, stream>>>(l_in_w, w_liw, 786432);
  castk<<<384, 256, 0, stream>>>(g_in_w, w_giw, 786432);
  castk<<<128, 256, 0, stream>>>(l_out_w, w_low, 262144);
  castk<<<128, 256, 0, stream>>>(g_out_w, w_gow, 262144);
  castk<<<256, 256, 0, stream>>>(gate_w, w_gt, 524288);

  // local branch (Q pre-scaled by c1)
  gemm_bt<<<dim3(128, 12), 256, 0, stream>>>(x_bf, w_liw, l_in_b, nullptr, qkv,
                                             TOK, 1536, 512, 512, c1);
  transpose_v<<<dim3(32, 32, 2), 256, 0, stream>>>(qkv, vt);
  attn_local<<<512, 256, 0, stream>>>(qkv, vt, ato);
  gemm_bt<<<dim3(128, 4), 256, 0, stream>>>(ato, w_low, l_out_b, locf, nullptr,
                                            TOK, 512, 512, 0, 1.f);
  resid_ln<<<4096, 256, 0, stream>>>(locf, x, n1_w, n1_b, lgbf);

  // global branch (Q pre-scaled by c1)
  gemm_bt<<<dim3(128, 12), 256, 0, stream>>>(x_bf, w_giw, g_in_b, nullptr, qkv,
                                             TOK, 1536, 512, 512, c1);
  transpose_v<<<dim3(32, 32, 2), 256, 0, stream>>>(qkv, vt);
  attn_global<<<512, 256, 0, stream>>>(qkv, vt, ato);
  gemm_bt<<<dim3(128, 4), 256, 0, stream>>>(ato, w_gow, g_out_b, glof, nullptr,
                                            TOK, 512, 512, 0, 1.f);
  resid_ln<<<4096, 256, 0, stream>>>(glof, x, n2_w, n2_b, lgbf + 512);

  // gate fusion
  gemm_bt<<<dim3(128, 4), 256, 0, stream>>>(lgbf, w_gt, gate_b, gpre, nullptr,
                                            TOK, 512, 1024, 0, 1.f);
  gate_final<<<4096, 256, 0, stream>>>(gpre, locf, glof, gln_w, gln_b, out);
}

// Round 8
// 466.710 us; speedup vs baseline: 1.2437x; 1.2437x over previous
//
#include <hip/hip_runtime.h>
#include <stdint.h>

// Problem constants
#define BB 8
#define SS 2048
#define FF 512
#define HH 4
#define TOK (BB * SS)   // 16384

typedef unsigned short u16;
typedef short short8 __attribute__((ext_vector_type(8)));
typedef float f32x4 __attribute__((ext_vector_type(4)));
typedef float f32x16 __attribute__((ext_vector_type(16)));
typedef unsigned int u32x4 __attribute__((ext_vector_type(4)));

static __device__ __forceinline__ u16 f2bf(float f) {
  uint32_t u = __builtin_bit_cast(uint32_t, f);
  u = (u + 0x7fffu + ((u >> 16) & 1u)) >> 16;
  return (u16)u;
}
static __device__ __forceinline__ float bf2f(u16 u) {
  return __builtin_bit_cast(float, (uint32_t)u << 16);
}

// packed f32x2 -> bf16x2 (RNE) in one instruction
static __device__ __forceinline__ uint32_t cvtpk(float lo, float hi) {
  uint32_t r;
  asm("v_cvt_pk_bf16_f32 %0, %1, %2" : "=v"(r) : "v"(lo), "v"(hi));
  return r;
}

// async global->LDS, 16B per lane. LDS dest = wave-uniform base + lane*16.
static __device__ __forceinline__ void cp16(void* lds, const void* g) {
  __builtin_amdgcn_global_load_lds(
      (const __attribute__((address_space(1))) void*)g,
      (__attribute__((address_space(3))) void*)lds, 16, 0, 0);
}

// ---------------------------------------------------------------- cast
__global__ __launch_bounds__(256) void castk(const float* __restrict__ s,
                                             u16* __restrict__ d, int n) {
  const int i = (blockIdx.x * 256 + threadIdx.x) * 8;
  if (i >= n) return;
  float4 a = *(const float4*)(s + i);
  float4 b = *(const float4*)(s + i + 4);
  short8 o;
  o[0] = (short)f2bf(a.x); o[1] = (short)f2bf(a.y);
  o[2] = (short)f2bf(a.z); o[3] = (short)f2bf(a.w);
  o[4] = (short)f2bf(b.x); o[5] = (short)f2bf(b.y);
  o[6] = (short)f2bf(b.z); o[7] = (short)f2bf(b.w);
  *(short8*)(d + i) = o;
}

// ---------------------------------------------------------------- GEMM
// C[M,N] = A[M,K](bf16) * B[N,K]^T(bf16) + bias.  128x128 tile, BK=64,
// 4 waves (2x2, 64x64 each), global_load_lds staging w/ XOR slot swizzle.
// Columns gn < qcols get scaled by qscale (used to pre-scale Q by log2e/sqrt(d)).
__global__ __launch_bounds__(256) void gemm_bt(
    const u16* __restrict__ A, const u16* __restrict__ B,
    const float* __restrict__ bias, float* __restrict__ Cf,
    u16* __restrict__ Cb, int M, int N, int K, int qcols, float qscale) {
  const int m0 = blockIdx.x << 7;
  const int n0 = blockIdx.y << 7;
  __shared__ u16 As[128 * 64];
  __shared__ u16 Bs[128 * 64];
  const int tid = threadIdx.x;
  const int wave = tid >> 6, lane = tid & 63;
  const int wr = wave >> 1, wc = wave & 1;

  f32x4 acc[4][4];
#pragma unroll
  for (int i = 0; i < 4; ++i)
#pragma unroll
    for (int j = 0; j < 4; ++j)
#pragma unroll
      for (int e = 0; e < 4; ++e) acc[i][j][e] = 0.f;

  for (int k0 = 0; k0 < K; k0 += 64) {
#pragma unroll
    for (int i = 0; i < 4; ++i) {
      const int base = (i * 4 + wave) << 10;       // wave-uniform LDS byte base
      const int lb = base + (lane << 4);
      const int r = lb >> 7;                       // row (128B rows)
      const int s = ((lb >> 4) & 7) ^ (r & 7);     // logical 16B slot
      cp16((char*)As + base, A + (size_t)(m0 + r) * K + k0 + s * 8);
      cp16((char*)Bs + base, B + (size_t)(n0 + r) * K + k0 + s * 8);
    }
    __syncthreads();
#pragma unroll
    for (int kk = 0; kk < 2; ++kk) {
      short8 af[4], bfr[4];
#pragma unroll
      for (int mi = 0; mi < 4; ++mi) {
        const int r = wr * 64 + mi * 16 + (lane & 15);
        const int p = (kk * 4 + (lane >> 4)) ^ (r & 7);
        af[mi] = *(const short8*)(As + r * 64 + p * 8);
      }
#pragma unroll
      for (int ni = 0; ni < 4; ++ni) {
        const int r = wc * 64 + ni * 16 + (lane & 15);
        const int p = (kk * 4 + (lane >> 4)) ^ (r & 7);
        bfr[ni] = *(const short8*)(Bs + r * 64 + p * 8);
      }
#pragma unroll
      for (int mi = 0; mi < 4; ++mi)
#pragma unroll
        for (int ni = 0; ni < 4; ++ni)
          acc[mi][ni] = __builtin_amdgcn_mfma_f32_16x16x32_bf16(
              af[mi], bfr[ni], acc[mi][ni], 0, 0, 0);
    }
    __syncthreads();
  }
  const int rv = (lane >> 4) << 2;
  const int cn = lane & 15;
#pragma unroll
  for (int mi = 0; mi < 4; ++mi)
#pragma unroll
    for (int ni = 0; ni < 4; ++ni) {
      const int gn = n0 + wc * 64 + ni * 16 + cn;
      const float bv = bias ? bias[gn] : 0.f;
      const float sc = (gn < qcols) ? qscale : 1.f;
#pragma unroll
      for (int v = 0; v < 4; ++v) {
        const int gm = m0 + wr * 64 + mi * 16 + rv + v;
        const size_t off = (size_t)gm * N + gn;
        const float val = (acc[mi][ni][v] + bv) * sc;
        if (Cf) Cf[off] = val;
        if (Cb) Cb[off] = f2bf(val);
      }
    }
}

// -------------------------------------------------- V transpose (per b,h)
// vt[bh][d][s] = qkv[(b*S+s)*1536 + 1024 + h*128 + d]
__global__ __launch_bounds__(256) void transpose_v(
    const u16* __restrict__ qkv, u16* __restrict__ vt) {
  const int bh = blockIdx.x, st = blockIdx.y, dt = blockIdx.z;
  const int b = bh >> 2, h = bh & 3;
  __shared__ u16 t[64][72];
  const int r = threadIdx.x >> 3;          // 0..31
  const int c8 = (threadIdx.x & 7) * 8;
#pragma unroll
  for (int ph = 0; ph < 2; ++ph) {
    const int srow = ph * 32 + r;
    const u16* src = qkv + (size_t)(b * SS + st * 64 + srow) * 1536 + 1024 +
                     h * 128 + dt * 64 + c8;
    *(short8*)&t[srow][c8] = *(const short8*)src;
  }
  __syncthreads();
#pragma unroll
  for (int ph = 0; ph < 2; ++ph) {
    const int drow = ph * 32 + r;
    short8 o;
#pragma unroll
    for (int j = 0; j < 8; ++j) o[j] = (short)t[c8 + j][drow];
    *(short8*)(vt + ((size_t)bh * 128 + dt * 64 + drow) * SS + st * 64 + c8) = o;
  }
}

// In-register P redistribution (T12): from swapped-QK score regs to PV
// A-fragment. For k-slice ks: block c0=(2ks)&3 serves dest half 0, c0+1 serves
// dest half 1; one permlane32_swap yields both output words.
template <typename GET>
static __device__ __forceinline__ short8 make_pa(int ks, GET get) {
  const int c0 = (2 * ks) & 3;
  u32x4 pw;
#pragma unroll
  for (int t = 0; t < 2; ++t) {
    uint32_t a = cvtpk(get(4 * c0 + 2 * t), get(4 * c0 + 2 * t + 1));
    uint32_t b = cvtpk(get(4 * (c0 + 1) + 2 * t), get(4 * (c0 + 1) + 2 * t + 1));
    auto r = __builtin_amdgcn_permlane32_swap(a, b, false, false);
    pw[t] = r[0];        // j = 2t, 2t+1
    pw[2 + t] = r[1];    // j = 4+2t, 5+2t
  }
  return __builtin_bit_cast(short8, pw);
}

// ---------------------------------------------------------- local attention
// one wave per (b, window, head); 32x32 scores, swapped QK^T, in-reg P (no LDS).
__global__ __launch_bounds__(256) void attn_local(
    const u16* __restrict__ qkv, const u16* __restrict__ vt,
    u16* __restrict__ ao) {
  const int wave = threadIdx.x >> 6, lane = threadIdx.x & 63;
  const int u = blockIdx.x * 4 + wave;
  const int b = u >> 8, w = (u >> 2) & 63, h = u & 3;
  const int q = lane & 31, half = lane >> 5;

  const size_t qbase = (size_t)(b * SS + w * 32 + q) * 1536 + h * 128;
  short8 qf[8];
#pragma unroll
  for (int d8 = 0; d8 < 8; ++d8)
    qf[d8] = *(const short8*)(qkv + qbase + d8 * 16 + half * 8);

  f32x16 s;
#pragma unroll
  for (int e = 0; e < 16; ++e) s[e] = 0.f;
  const size_t kbase = qbase + 512;
#pragma unroll
  for (int d8 = 0; d8 < 8; ++d8) {
    short8 kf = *(const short8*)(qkv + kbase + d8 * 16 + half * 8);
    s = __builtin_amdgcn_mfma_f32_32x32x16_bf16(kf, qf[d8], s, 0, 0, 0);
  }
  // Q pre-scaled by log2e/sqrt(128) in GEMM epilogue -> scores already in log2 domain
  float m = s[0];
#pragma unroll
  for (int e = 1; e < 16; ++e) m = fmaxf(m, s[e]);
  m = fmaxf(m, __shfl_xor(m, 32));
  float l = 0.f;
#pragma unroll
  for (int e = 0; e < 16; ++e) { s[e] = exp2f(s[e] - m); l += s[e]; }
  l += __shfl_xor(l, 32);

  f32x16 o[4];
#pragma unroll
  for (int nt = 0; nt < 4; ++nt)
#pragma unroll
    for (int e = 0; e < 16; ++e) o[nt][e] = 0.f;
  const size_t vbase = ((size_t)(b * 4 + h) * 128) * SS + w * 32;
#pragma unroll
  for (int ks = 0; ks < 2; ++ks) {
    short8 pa = make_pa(ks, [&](int e) { return s[e]; });
#pragma unroll
    for (int nt = 0; nt < 4; ++nt) {
      short8 vb = *(const short8*)(vt + vbase + (size_t)(nt * 32 + q) * SS +
                                   ks * 16 + half * 8);
      o[nt] = __builtin_amdgcn_mfma_f32_32x32x16_bf16(pa, vb, o[nt], 0, 0, 0);
    }
  }
  const float rl = 1.f / l;
  const size_t ob = (size_t)(b * SS + w * 32) * FF + h * 128;
#pragma unroll
  for (int e = 0; e < 16; ++e) {
    const int qr = (e & 3) + 8 * (e >> 2) + 4 * half;
    const float rf = __shfl(rl, qr);
#pragma unroll
    for (int nt = 0; nt < 4; ++nt)
      ao[ob + (size_t)qr * FF + nt * 32 + q] = f2bf(o[nt][e] * rf);
  }
}

// --------------------------------------------------------- global attention
// flash-style; block = (b,h,qtile128), 4 waves x 32 q-rows; ktile=64.
// Double-buffered K/V LDS (R5 verified structure), 1 barrier/tile;
// in-reg P (T12); defer-max (T13); tree reductions; setprio around MFMA (T5).
__global__ __launch_bounds__(256) void attn_global(
    const u16* __restrict__ qkv, const u16* __restrict__ vt,
    u16* __restrict__ ao) {
  // XCD swizzle: 512 blocks, 64 consecutive logical blocks (4 bh pairs) per XCD
  const int lb = (blockIdx.x & 7) * 64 + (blockIdx.x >> 3);
  const int bh = lb >> 4, qt = lb & 15;
  const int b = bh >> 2, h = bh & 3;
  const int wave = threadIdx.x >> 6, lane = threadIdx.x & 63;
  const int q = lane & 31, half = lane >> 5;

  __shared__ u16 Ks[2][64 * 128];
  __shared__ u16 Vs[2][128 * 64];

  short8 qf[8];
  const size_t qb = (size_t)(b * SS + qt * 128 + wave * 32 + q) * 1536 + h * 128;
#pragma unroll
  for (int d8 = 0; d8 < 8; ++d8)
    qf[d8] = *(const short8*)(qkv + qb + d8 * 16 + half * 8);

  f32x16 o[4];
#pragma unroll
  for (int nt = 0; nt < 4; ++nt)
#pragma unroll
    for (int e = 0; e < 16; ++e) o[nt][e] = 0.f;
  float m = -3e38f, lsum = 0.f;

  const size_t kbase = (size_t)b * SS * 1536 + 512 + h * 128;
  const size_t vbase = (size_t)bh * 128 * SS;

  auto STAGE = [&](int kt, int bsel) {
    u16* kd = Ks[bsel];
    u16* vd = Vs[bsel];
#pragma unroll
    for (int i = 0; i < 4; ++i) {
      const int base = (i * 4 + wave) << 10;
      const int lbk = base + (lane << 4);
      {
        const int r = lbk >> 8;                       // K rows 256B
        const int sl = ((lbk >> 4) & 15) ^ (r & 7);
        cp16((char*)kd + base,
             qkv + kbase + (size_t)(kt * 64 + r) * 1536 + sl * 8);
      }
      {
        const int d = lbk >> 7;                       // V^T rows 128B
        const int sl = ((lbk >> 4) & 7) ^ (d & 7);
        cp16((char*)vd + base, vt + vbase + (size_t)d * SS + kt * 64 + sl * 8);
      }
    }
  };
  STAGE(0, 0);
  __syncthreads();
  for (int kt = 0; kt < 32; ++kt) {
    const int cur = kt & 1;
    if (kt + 1 < 32) STAGE(kt + 1, cur ^ 1);    // issue next tile's loads early
    const u16* Kb = Ks[cur];
    const u16* Vb = Vs[cur];

    f32x16 sa[2];
#pragma unroll
    for (int mt = 0; mt < 2; ++mt)
#pragma unroll
      for (int e = 0; e < 16; ++e) sa[mt][e] = 0.f;
    __builtin_amdgcn_s_setprio(1);
#pragma unroll
    for (int mt = 0; mt < 2; ++mt) {
      const int kr = mt * 32 + q;
#pragma unroll
      for (int d8 = 0; d8 < 8; ++d8) {
        const int ps = (d8 * 2 + half) ^ (kr & 7);
        short8 kf = *(const short8*)(Kb + kr * 128 + ps * 8);
        sa[mt] = __builtin_amdgcn_mfma_f32_32x32x16_bf16(kf, qf[d8], sa[mt], 0, 0, 0);
      }
    }
    __builtin_amdgcn_s_setprio(0);
    // ---- online softmax, log2 domain (Q pre-scaled), defer-max THR=8
    // tree reductions (depth 5) instead of 31-deep serial chains
    float t[16];
#pragma unroll
    for (int e = 0; e < 16; ++e) t[e] = fmaxf(sa[0][e], sa[1][e]);
#pragma unroll
    for (int st = 8; st >= 1; st >>= 1)
#pragma unroll
      for (int e = 0; e < 8; ++e)
        if (e < st) t[e] = fmaxf(t[e], t[e + st]);
    float pmax = fmaxf(t[0], __shfl_xor(t[0], 32));
    if (__any(pmax > m + 8.f)) {
      const float mn = fmaxf(m, pmax);
      const float corr = exp2f(m - mn);
      m = mn;
      lsum *= corr;
#pragma unroll
      for (int e = 0; e < 16; ++e) {
        const float cf = __shfl(corr, (e & 3) + 8 * (e >> 2) + 4 * half);
#pragma unroll
        for (int nt = 0; nt < 4; ++nt) o[nt][e] *= cf;
      }
    }
#pragma unroll
    for (int mt = 0; mt < 2; ++mt)
#pragma unroll
      for (int e = 0; e < 16; ++e) sa[mt][e] = exp2f(sa[mt][e] - m);
    float u[16];
#pragma unroll
    for (int e = 0; e < 16; ++e) u[e] = sa[0][e] + sa[1][e];
#pragma unroll
    for (int st = 8; st >= 1; st >>= 1)
#pragma unroll
      for (int e = 0; e < 8; ++e)
        if (e < st) u[e] += u[e + st];
    lsum += u[0] + __shfl_xor(u[0], 32);
    // ---- P -> PV A-fragments in-register; PV
    __builtin_amdgcn_s_setprio(1);
#pragma unroll
    for (int ks = 0; ks < 4; ++ks) {
      const int mt = ks >> 1;
      short8 pa = make_pa(ks, [&](int e) { return sa[mt][e]; });
#pragma unroll
      for (int nt = 0; nt < 4; ++nt) {
        const int d = nt * 32 + q;
        const int ps = (ks * 2 + half) ^ (d & 7);
        short8 vb = *(const short8*)(Vb + d * 64 + ps * 8);
        o[nt] = __builtin_amdgcn_mfma_f32_32x32x16_bf16(pa, vb, o[nt], 0, 0, 0);
      }
    }
    __builtin_amdgcn_s_setprio(0);
    __syncthreads();  // drains vmcnt(0): next buffer staged, cur free to reuse
  }
  const float rl = 1.f / lsum;
  const size_t ob = (size_t)(b * SS + qt * 128 + wave * 32) * FF + h * 128;
#pragma unroll
  for (int e = 0; e < 16; ++e) {
    const int qr = (e & 3) + 8 * (e >> 2) + 4 * half;
    const float rf = __shfl(rl, qr);
#pragma unroll
    for (int nt = 0; nt < 4; ++nt)
      ao[ob + (size_t)qr * FF + nt * 32 + q] = f2bf(o[nt][e] * rf);
  }
}

// --------------- residual + LayerNorm: bf16 attn-proj in, bf16 LN out only
__global__ __launch_bounds__(256) void resid_ln(
    const u16* __restrict__ yb, const float* __restrict__ x,
    const float* __restrict__ w, const float* __restrict__ bv_,
    u16* __restrict__ lg) {
  const int wave = threadIdx.x >> 6, lane = threadIdx.x & 63;
  const size_t row = (size_t)blockIdx.x * 4 + wave;
  const int c = lane * 8;
  const u16* yr = yb + row * FF;
  const float* xr = x + row * FF;
  float v[8];
  {
    short8 a = *(const short8*)(yr + c);
    float4 b0 = *(const float4*)(xr + c), b1 = *(const float4*)(xr + c + 4);
    v[0] = bf2f((u16)a[0]) + b0.x; v[1] = bf2f((u16)a[1]) + b0.y;
    v[2] = bf2f((u16)a[2]) + b0.z; v[3] = bf2f((u16)a[3]) + b0.w;
    v[4] = bf2f((u16)a[4]) + b1.x; v[5] = bf2f((u16)a[5]) + b1.y;
    v[6] = bf2f((u16)a[6]) + b1.z; v[7] = bf2f((u16)a[7]) + b1.w;
  }
  float s = 0.f, s2 = 0.f;
#pragma unroll
  for (int e = 0; e < 8; ++e) { s += v[e]; s2 += v[e] * v[e]; }
#pragma unroll
  for (int off = 1; off < 64; off <<= 1) {
    s += __shfl_xor(s, off);
    s2 += __shfl_xor(s2, off);
  }
  const float mu = s * (1.f / 512.f);
  const float var = s2 * (1.f / 512.f) - mu * mu;
  const float rs = rsqrtf(var + 1e-5f);
  float4 w0 = *(const float4*)(w + c), w1 = *(const float4*)(w + c + 4);
  float4 b0 = *(const float4*)(bv_ + c), b1 = *(const float4*)(bv_ + c + 4);
  const float wv[8] = {w0.x, w0.y, w0.z, w0.w, w1.x, w1.y, w1.z, w1.w};
  const float bb[8] = {b0.x, b0.y, b0.z, b0.w, b1.x, b1.y, b1.z, b1.w};
  short8 ob;
#pragma unroll
  for (int e = 0; e < 8; ++e)
    ob[e] = (short)f2bf((v[e] - mu) * rs * wv[e] + bb[e]);
  *(short8*)(lg + row * 1024 + c) = ob;
}

// ------------------- gate LN + sigmoid + mix (local/glob read as bf16)
__global__ __launch_bounds__(256) void gate_final(
    const float* __restrict__ gp, const u16* __restrict__ lg,
    const float* __restrict__ w, const float* __restrict__ bv_,
    float* __restrict__ out) {
  const int wave = threadIdx.x >> 6, lane = threadIdx.x & 63;
  const size_t row = (size_t)blockIdx.x * 4 + wave;
  const int c = lane * 8;
  const float* gr = gp + row * FF;
  float v[8];
  {
    float4 a0 = *(const float4*)(gr + c), a1 = *(const float4*)(gr + c + 4);
    v[0] = a0.x; v[1] = a0.y; v[2] = a0.z; v[3] = a0.w;
    v[4] = a1.x; v[5] = a1.y; v[6] = a1.z; v[7] = a1.w;
  }
  float s = 0.f, s2 = 0.f;
#pragma unroll
  for (int e = 0; e < 8; ++e) { s += v[e]; s2 += v[e] * v[e]; }
#pragma unroll
  for (int off = 1; off < 64; off <<= 1) {
    s += __shfl_xor(s, off);
    s2 += __shfl_xor(s2, off);
  }
  const float mu = s * (1.f / 512.f);
  const float var = s2 * (1.f / 512.f) - mu * mu;
  const float rs = rsqrtf(var + 1e-5f);
  float4 w0 = *(const float4*)(w + c), w1 = *(const float4*)(w + c + 4);
  float4 b0 = *(const float4*)(bv_ + c), b1 = *(const float4*)(bv_ + c + 4);
  const float wv[8] = {w0.x, w0.y, w0.z, w0.w, w1.x, w1.y, w1.z, w1.w};
  const float bb[8] = {b0.x, b0.y, b0.z, b0.w, b1.x, b1.y, b1.z, b1.w};
  short8 l8 = *(const short8*)(lg + row * 1024 + c);
  short8 g8 = *(const short8*)(lg + row * 1024 + 512 + c);
  float r[8];
#pragma unroll
  for (int e = 0; e < 8; ++e) {
    const float z = (v[e] - mu) * rs * wv[e] + bb[e];
    const float gt = 1.f / (1.f + exp2f(-1.44269504f * z));
    r[e] = gt * bf2f((u16)l8[e]) + (1.f - gt) * bf2f((u16)g8[e]);
  }
  *(float4*)(out + row * FF + c) = make_float4(r[0], r[1], r[2], r[3]);
  *(float4*)(out + row * FF + c + 4) = make_float4(r[4], r[5], r[6], r[7]);
}

// ---------------------------------------------------------------- launch
extern "C" void kernel_launch(void* const* d_in, const int* in_sizes, int n_in,
                              void* d_out, int out_size, void* d_ws,
                              size_t ws_size, hipStream_t stream) {
  const float* x       = (const float*)d_in[0];
  const float* l_in_w  = (const float*)d_in[1];
  const float* l_in_b  = (const float*)d_in[2];
  const float* l_out_w = (const float*)d_in[3];
  const float* l_out_b = (const float*)d_in[4];
  const float* g_in_w  = (const float*)d_in[5];
  const float* g_in_b  = (const float*)d_in[6];
  const float* g_out_w = (const float*)d_in[7];
  const float* g_out_b = (const float*)d_in[8];
  const float* n1_w    = (const float*)d_in[9];
  const float* n1_b    = (const float*)d_in[10];
  const float* n2_w    = (const float*)d_in[11];
  const float* n2_b    = (const float*)d_in[12];
  const float* gate_w  = (const float*)d_in[13];
  const float* gate_b  = (const float*)d_in[14];
  const float* gln_w   = (const float*)d_in[15];
  const float* gln_b   = (const float*)d_in[16];
  float* out = (float*)d_out;

  const float c1 = 0.12752724808f;  // log2(e)/sqrt(128)

  char* ws = (char*)d_ws;
  u16* x_bf  = (u16*)(ws);                      // 16 MB
  u16* w_liw = (u16*)(ws + 16777216);
  u16* w_giw = (u16*)(ws + 18350080);
  u16* w_low = (u16*)(ws + 19922944);
  u16* w_gow = (u16*)(ws + 20447232);
  u16* w_gt  = (u16*)(ws + 20971520);
  u16* qkv   = (u16*)(ws + 22020096);           // 48 MB (reused per branch)
  u16* vt    = (u16*)(ws + 72351744);           // 16 MB (V^T; reused)
  u16* ato   = (u16*)(ws + 89128960);           // 16 MB attn out (reused)
  u16* prj   = (u16*)(ws + 105906176);          // 16 MB bf16 attn-proj out (reused)
  u16* lgbf  = (u16*)(ws + 122683392);          // 32 MB [local|glob] bf16 LN out
  float* gpre = (float*)(ws + 22020096);        // alias qkv (free by then)

  castk<<<4096, 256, 0, stream>>>(x, x_bf, 8388608);
  castk<<<384, 256, 0, stream>>>(l_in_w, w_liw, 786432);
  castk<<<384, 256, 0, stream>>>(g_in_w, w_giw, 786432);
  castk<<<128, 256, 0, stream>>>(l_out_w, w_low, 262144);
  castk<<<128, 256, 0, stream>>>(g_out_w, w_gow, 262144);
  castk<<<256, 256, 0, stream>>>(gate_w, w_gt, 524288);

  // local branch (Q pre-scaled by c1)
  gemm_bt<<<dim3(128, 12), 256, 0, stream>>>(x_bf, w_liw, l_in_b, nullptr, qkv,
                                             TOK, 1536, 512, 512, c1);
  transpose_v<<<dim3(32, 32, 2), 256, 0, stream>>>(qkv, vt);
  attn_local<<<512, 256, 0, stream>>>(qkv, vt, ato);
  gemm_bt<<<dim3(128, 4), 256, 0, stream>>>(ato, w_low, l_out_b, nullptr, prj,
                                            TOK, 512, 512, 0, 1.f);
  resid_ln<<<4096, 256, 0, stream>>>(prj, x, n1_w, n1_b, lgbf);

  // global branch (Q pre-scaled by c1)
  gemm_bt<<<dim3(128, 12), 256, 0, stream>>>(x_bf, w_giw, g_in_b, nullptr, qkv,
                                             TOK, 1536, 512, 512, c1);
  transpose_v<<<dim3(32, 32, 2), 256, 0, stream>>>(qkv, vt);
  attn_global<<<512, 256, 0, stream>>>(qkv, vt, ato);
  gemm_bt<<<dim3(128, 4), 256, 0, stream>>>(ato, w_gow, g_out_b, nullptr, prj,
                                            TOK, 512, 512, 0, 1.f);
  resid_ln<<<4096, 256, 0, stream>>>(prj, x, n2_w, n2_b, lgbf + 512);

  // gate fusion
  gemm_bt<<<dim3(128, 4), 256, 0, stream>>>(lgbf, w_gt, gate_b, gpre, nullptr,
                                            TOK, 512, 1024, 0, 1.f);
  gate_final<<<4096, 256, 0, stream>>>(gpre, lgbf, gln_w, gln_b, out);
}

// Round 10
// 443.377 us; speedup vs baseline: 1.3092x; 1.0526x over previous
//
#include <hip/hip_runtime.h>
#include <stdint.h>

// Problem constants
#define BB 8
#define SS 2048
#define FF 512
#define HH 4
#define TOK (BB * SS)   // 16384
#define QST 3072        // fused qkv row stride (local 0:1536 | global 1536:3072)

typedef unsigned short u16;
typedef short short8 __attribute__((ext_vector_type(8)));
typedef float f32x4 __attribute__((ext_vector_type(4)));
typedef float f32x16 __attribute__((ext_vector_type(16)));
typedef unsigned int u32x4 __attribute__((ext_vector_type(4)));

static __device__ __forceinline__ u16 f2bf(float f) {
  uint32_t u = __builtin_bit_cast(uint32_t, f);
  u = (u + 0x7fffu + ((u >> 16) & 1u)) >> 16;
  return (u16)u;
}
static __device__ __forceinline__ float bf2f(u16 u) {
  return __builtin_bit_cast(float, (uint32_t)u << 16);
}

// packed f32x2 -> bf16x2 (RNE) in one instruction
static __device__ __forceinline__ uint32_t cvtpk(float lo, float hi) {
  uint32_t r;
  asm("v_cvt_pk_bf16_f32 %0, %1, %2" : "=v"(r) : "v"(lo), "v"(hi));
  return r;
}

// async global->LDS, 16B per lane. LDS dest = wave-uniform base + lane*16.
static __device__ __forceinline__ void cp16(void* lds, const void* g) {
  __builtin_amdgcn_global_load_lds(
      (const __attribute__((address_space(1))) void*)g,
      (__attribute__((address_space(3))) void*)lds, 16, 0, 0);
}

// ---------------------------------------------------------------- cast
__global__ __launch_bounds__(256) void castk(const float* __restrict__ s,
                                             u16* __restrict__ d, int n) {
  const int i = (blockIdx.x * 256 + threadIdx.x) * 8;
  if (i >= n) return;
  float4 a = *(const float4*)(s + i);
  float4 b = *(const float4*)(s + i + 4);
  short8 o;
  o[0] = (short)f2bf(a.x); o[1] = (short)f2bf(a.y);
  o[2] = (short)f2bf(a.z); o[3] = (short)f2bf(a.w);
  o[4] = (short)f2bf(b.x); o[5] = (short)f2bf(b.y);
  o[6] = (short)f2bf(b.z); o[7] = (short)f2bf(b.w);
  *(short8*)(d + i) = o;
}

// ---------------------------------------------------------------- GEMM
// C[M,N] = A[M,K](bf16) * B[N,K]^T(bf16) + bias, bf16 out.  128x128 tile,
// BK=64, 4 waves (2x2), global_load_lds staging w/ XOR slot swizzle.
// Columns gn>=nsplit take bias2[gn-nsplit]; effective col cg = gn mod nsplit;
// cg<qcols scaled by qscale (pre-scales Q of both branches by log2e/sqrt(d)).
__global__ __launch_bounds__(256) void gemm_bt(
    const u16* __restrict__ A, const u16* __restrict__ B,
    const float* __restrict__ bias, const float* __restrict__ bias2,
    u16* __restrict__ Cb, int M, int N, int K, int nsplit, int qcols,
    float qscale) {
  const int m0 = blockIdx.x << 7;
  const int n0 = blockIdx.y << 7;
  __shared__ u16 As[128 * 64];
  __shared__ u16 Bs[128 * 64];
  const int tid = threadIdx.x;
  const int wave = tid >> 6, lane = tid & 63;
  const int wr = wave >> 1, wc = wave & 1;

  f32x4 acc[4][4];
#pragma unroll
  for (int i = 0; i < 4; ++i)
#pragma unroll
    for (int j = 0; j < 4; ++j)
#pragma unroll
      for (int e = 0; e < 4; ++e) acc[i][j][e] = 0.f;

  for (int k0 = 0; k0 < K; k0 += 64) {
#pragma unroll
    for (int i = 0; i < 4; ++i) {
      const int base = (i * 4 + wave) << 10;       // wave-uniform LDS byte base
      const int lb = base + (lane << 4);
      const int r = lb >> 7;                       // row (128B rows)
      const int s = ((lb >> 4) & 7) ^ (r & 7);     // logical 16B slot
      cp16((char*)As + base, A + (size_t)(m0 + r) * K + k0 + s * 8);
      cp16((char*)Bs + base, B + (size_t)(n0 + r) * K + k0 + s * 8);
    }
    __syncthreads();
#pragma unroll
    for (int kk = 0; kk < 2; ++kk) {
      short8 af[4], bfr[4];
#pragma unroll
      for (int mi = 0; mi < 4; ++mi) {
        const int r = wr * 64 + mi * 16 + (lane & 15);
        const int p = (kk * 4 + (lane >> 4)) ^ (r & 7);
        af[mi] = *(const short8*)(As + r * 64 + p * 8);
      }
#pragma unroll
      for (int ni = 0; ni < 4; ++ni) {
        const int r = wc * 64 + ni * 16 + (lane & 15);
        const int p = (kk * 4 + (lane >> 4)) ^ (r & 7);
        bfr[ni] = *(const short8*)(Bs + r * 64 + p * 8);
      }
#pragma unroll
      for (int mi = 0; mi < 4; ++mi)
#pragma unroll
        for (int ni = 0; ni < 4; ++ni)
          acc[mi][ni] = __builtin_amdgcn_mfma_f32_16x16x32_bf16(
              af[mi], bfr[ni], acc[mi][ni], 0, 0, 0);
    }
    __syncthreads();
  }
  const int rv = (lane >> 4) << 2;
  const int cn = lane & 15;
#pragma unroll
  for (int mi = 0; mi < 4; ++mi)
#pragma unroll
    for (int ni = 0; ni < 4; ++ni) {
      const int gn = n0 + wc * 64 + ni * 16 + cn;
      const int cg = (gn >= nsplit) ? gn - nsplit : gn;
      const float bv = (gn >= nsplit) ? bias2[cg] : bias[cg];
      const float sc = (cg < qcols) ? qscale : 1.f;
#pragma unroll
      for (int v = 0; v < 4; ++v) {
        const int gm = m0 + wr * 64 + mi * 16 + rv + v;
        Cb[(size_t)gm * N + gn] = f2bf((acc[mi][ni][v] + bv) * sc);
      }
    }
}

// -------------------------------------------------- V transpose (per b,h)
// vt[bh][d][s] = qkvp[(b*S+s)*QST + 1024 + h*128 + d]   (qkvp pre-offset by branch)
__global__ __launch_bounds__(256) void transpose_v(
    const u16* __restrict__ qkvp, u16* __restrict__ vt) {
  const int bh = blockIdx.x, st = blockIdx.y, dt = blockIdx.z;
  const int b = bh >> 2, h = bh & 3;
  __shared__ u16 t[64][72];
  const int r = threadIdx.x >> 3;          // 0..31
  const int c8 = (threadIdx.x & 7) * 8;
#pragma unroll
  for (int ph = 0; ph < 2; ++ph) {
    const int srow = ph * 32 + r;
    const u16* src = qkvp + (size_t)(b * SS + st * 64 + srow) * QST + 1024 +
                     h * 128 + dt * 64 + c8;
    *(short8*)&t[srow][c8] = *(const short8*)src;
  }
  __syncthreads();
#pragma unroll
  for (int ph = 0; ph < 2; ++ph) {
    const int drow = ph * 32 + r;
    short8 o;
#pragma unroll
    for (int j = 0; j < 8; ++j) o[j] = (short)t[c8 + j][drow];
    *(short8*)(vt + ((size_t)bh * 128 + dt * 64 + drow) * SS + st * 64 + c8) = o;
  }
}

// In-register P redistribution (T12): from swapped-QK score regs to PV
// A-fragment. For k-slice ks: block c0=(2ks)&3 serves dest half 0, c0+1 serves
// dest half 1; one permlane32_swap yields both output words.
template <typename GET>
static __device__ __forceinline__ short8 make_pa(int ks, GET get) {
  const int c0 = (2 * ks) & 3;
  u32x4 pw;
#pragma unroll
  for (int t = 0; t < 2; ++t) {
    uint32_t a = cvtpk(get(4 * c0 + 2 * t), get(4 * c0 + 2 * t + 1));
    uint32_t b = cvtpk(get(4 * (c0 + 1) + 2 * t), get(4 * (c0 + 1) + 2 * t + 1));
    auto r = __builtin_amdgcn_permlane32_swap(a, b, false, false);
    pw[t] = r[0];        // j = 2t, 2t+1
    pw[2 + t] = r[1];    // j = 4+2t, 5+2t
  }
  return __builtin_bit_cast(short8, pw);
}

// ---------------------------------------------------------- local attention
// one wave per (b, window, head); 32x32 scores, swapped QK^T, in-reg P (no LDS).
__global__ __launch_bounds__(256) void attn_local(
    const u16* __restrict__ qkv, const u16* __restrict__ vt,
    u16* __restrict__ ao) {
  const int wave = threadIdx.x >> 6, lane = threadIdx.x & 63;
  const int u = blockIdx.x * 4 + wave;
  const int b = u >> 8, w = (u >> 2) & 63, h = u & 3;
  const int q = lane & 31, half = lane >> 5;

  const size_t qbase = (size_t)(b * SS + w * 32 + q) * QST + h * 128;
  short8 qf[8];
#pragma unroll
  for (int d8 = 0; d8 < 8; ++d8)
    qf[d8] = *(const short8*)(qkv + qbase + d8 * 16 + half * 8);

  f32x16 s;
#pragma unroll
  for (int e = 0; e < 16; ++e) s[e] = 0.f;
  const size_t kbase = qbase + 512;
#pragma unroll
  for (int d8 = 0; d8 < 8; ++d8) {
    short8 kf = *(const short8*)(qkv + kbase + d8 * 16 + half * 8);
    s = __builtin_amdgcn_mfma_f32_32x32x16_bf16(kf, qf[d8], s, 0, 0, 0);
  }
  // Q pre-scaled by log2e/sqrt(128) in GEMM epilogue -> scores in log2 domain
  float m = s[0];
#pragma unroll
  for (int e = 1; e < 16; ++e) m = fmaxf(m, s[e]);
  m = fmaxf(m, __shfl_xor(m, 32));
  float l = 0.f;
#pragma unroll
  for (int e = 0; e < 16; ++e) { s[e] = exp2f(s[e] - m); l += s[e]; }
  l += __shfl_xor(l, 32);

  f32x16 o[4];
#pragma unroll
  for (int nt = 0; nt < 4; ++nt)
#pragma unroll
    for (int e = 0; e < 16; ++e) o[nt][e] = 0.f;
  const size_t vbase = ((size_t)(b * 4 + h) * 128) * SS + w * 32;
#pragma unroll
  for (int ks = 0; ks < 2; ++ks) {
    short8 pa = make_pa(ks, [&](int e) { return s[e]; });
#pragma unroll
    for (int nt = 0; nt < 4; ++nt) {
      short8 vb = *(const short8*)(vt + vbase + (size_t)(nt * 32 + q) * SS +
                                   ks * 16 + half * 8);
      o[nt] = __builtin_amdgcn_mfma_f32_32x32x16_bf16(pa, vb, o[nt], 0, 0, 0);
    }
  }
  const float rl = 1.f / l;
  const size_t ob = (size_t)(b * SS + w * 32) * FF + h * 128;
#pragma unroll
  for (int e = 0; e < 16; ++e) {
    const int qr = (e & 3) + 8 * (e >> 2) + 4 * half;
    const float rf = __shfl(rl, qr);
#pragma unroll
    for (int nt = 0; nt < 4; ++nt)
      ao[ob + (size_t)qr * FF + nt * 32 + q] = f2bf(o[nt][e] * rf);
  }
}

// --------------------------------------------------------- global attention
// flash-style; block = (b,h,qtile128), 4 waves x 32 q-rows; ktile=64.
// Double-buffered K/V LDS (R5 verified structure), 1 barrier/tile;
// in-reg P (T12); defer-max (T13); tree reductions. (setprio reverted: hurts
// barrier-lockstep structures, R8 post-mortem / m190.)
__global__ __launch_bounds__(256) void attn_global(
    const u16* __restrict__ qkv, const u16* __restrict__ vt,
    u16* __restrict__ ao) {
  // XCD swizzle: 512 blocks, 64 consecutive logical blocks (4 bh pairs) per XCD
  const int lb = (blockIdx.x & 7) * 64 + (blockIdx.x >> 3);
  const int bh = lb >> 4, qt = lb & 15;
  const int b = bh >> 2, h = bh & 3;
  const int wave = threadIdx.x >> 6, lane = threadIdx.x & 63;
  const int q = lane & 31, half = lane >> 5;

  __shared__ u16 Ks[2][64 * 128];
  __shared__ u16 Vs[2][128 * 64];

  short8 qf[8];
  const size_t qb =
      (size_t)(b * SS + qt * 128 + wave * 32 + q) * QST + 1536 + h * 128;
#pragma unroll
  for (int d8 = 0; d8 < 8; ++d8)
    qf[d8] = *(const short8*)(qkv + qb + d8 * 16 + half * 8);

  f32x16 o[4];
#pragma unroll
  for (int nt = 0; nt < 4; ++nt)
#pragma unroll
    for (int e = 0; e < 16; ++e) o[nt][e] = 0.f;
  float m = -3e38f, lsum = 0.f;

  const size_t kbase = (size_t)b * SS * QST + 1536 + 512 + h * 128;
  const size_t vbase = (size_t)bh * 128 * SS;

  auto STAGE = [&](int kt, int bsel) {
    u16* kd = Ks[bsel];
    u16* vd = Vs[bsel];
#pragma unroll
    for (int i = 0; i < 4; ++i) {
      const int base = (i * 4 + wave) << 10;
      const int lbk = base + (lane << 4);
      {
        const int r = lbk >> 8;                       // K rows 256B
        const int sl = ((lbk >> 4) & 15) ^ (r & 7);
        cp16((char*)kd + base,
             qkv + kbase + (size_t)(kt * 64 + r) * QST + sl * 8);
      }
      {
        const int d = lbk >> 7;                       // V^T rows 128B
        const int sl = ((lbk >> 4) & 7) ^ (d & 7);
        cp16((char*)vd + base, vt + vbase + (size_t)d * SS + kt * 64 + sl * 8);
      }
    }
  };
  STAGE(0, 0);
  __syncthreads();
  for (int kt = 0; kt < 32; ++kt) {
    const int cur = kt & 1;
    if (kt + 1 < 32) STAGE(kt + 1, cur ^ 1);    // issue next tile's loads early
    const u16* Kb = Ks[cur];
    const u16* Vb = Vs[cur];

    f32x16 sa[2];
#pragma unroll
    for (int mt = 0; mt < 2; ++mt)
#pragma unroll
      for (int e = 0; e < 16; ++e) sa[mt][e] = 0.f;
#pragma unroll
    for (int mt = 0; mt < 2; ++mt) {
      const int kr = mt * 32 + q;
#pragma unroll
      for (int d8 = 0; d8 < 8; ++d8) {
        const int ps = (d8 * 2 + half) ^ (kr & 7);
        short8 kf = *(const short8*)(Kb + kr * 128 + ps * 8);
        sa[mt] = __builtin_amdgcn_mfma_f32_32x32x16_bf16(kf, qf[d8], sa[mt], 0, 0, 0);
      }
    }
    // ---- online softmax, log2 domain (Q pre-scaled), defer-max THR=8
    // tree reductions (depth 5) instead of 31-deep serial chains
    float t[16];
#pragma unroll
    for (int e = 0; e < 16; ++e) t[e] = fmaxf(sa[0][e], sa[1][e]);
#pragma unroll
    for (int st = 8; st >= 1; st >>= 1)
#pragma unroll
      for (int e = 0; e < 8; ++e)
        if (e < st) t[e] = fmaxf(t[e], t[e + st]);
    float pmax = fmaxf(t[0], __shfl_xor(t[0], 32));
    if (__any(pmax > m + 8.f)) {
      const float mn = fmaxf(m, pmax);
      const float corr = exp2f(m - mn);
      m = mn;
      lsum *= corr;
#pragma unroll
      for (int e = 0; e < 16; ++e) {
        const float cf = __shfl(corr, (e & 3) + 8 * (e >> 2) + 4 * half);
#pragma unroll
        for (int nt = 0; nt < 4; ++nt) o[nt][e] *= cf;
      }
    }
#pragma unroll
    for (int mt = 0; mt < 2; ++mt)
#pragma unroll
      for (int e = 0; e < 16; ++e) sa[mt][e] = exp2f(sa[mt][e] - m);
    float u[16];
#pragma unroll
    for (int e = 0; e < 16; ++e) u[e] = sa[0][e] + sa[1][e];
#pragma unroll
    for (int st = 8; st >= 1; st >>= 1)
#pragma unroll
      for (int e = 0; e < 8; ++e)
        if (e < st) u[e] += u[e + st];
    lsum += u[0] + __shfl_xor(u[0], 32);
    // ---- P -> PV A-fragments in-register; PV
#pragma unroll
    for (int ks = 0; ks < 4; ++ks) {
      const int mt = ks >> 1;
      short8 pa = make_pa(ks, [&](int e) { return sa[mt][e]; });
#pragma unroll
      for (int nt = 0; nt < 4; ++nt) {
        const int d = nt * 32 + q;
        const int ps = (ks * 2 + half) ^ (d & 7);
        short8 vb = *(const short8*)(Vb + d * 64 + ps * 8);
        o[nt] = __builtin_amdgcn_mfma_f32_32x32x16_bf16(pa, vb, o[nt], 0, 0, 0);
      }
    }
    __syncthreads();  // drains vmcnt(0): next buffer staged, cur free to reuse
  }
  const float rl = 1.f / lsum;
  const size_t ob = (size_t)(b * SS + qt * 128 + wave * 32) * FF + h * 128;
#pragma unroll
  for (int e = 0; e < 16; ++e) {
    const int qr = (e & 3) + 8 * (e >> 2) + 4 * half;
    const float rf = __shfl(rl, qr);
#pragma unroll
    for (int nt = 0; nt < 4; ++nt)
      ao[ob + (size_t)qr * FF + nt * 32 + q] = f2bf(o[nt][e] * rf);
  }
}

// --------------- residual + LayerNorm: bf16 attn-proj in, bf16 LN out only
__global__ __launch_bounds__(256) void resid_ln(
    const u16* __restrict__ yb, const float* __restrict__ x,
    const float* __restrict__ w, const float* __restrict__ bv_,
    u16* __restrict__ lg) {
  const int wave = threadIdx.x >> 6, lane = threadIdx.x & 63;
  const size_t row = (size_t)blockIdx.x * 4 + wave;
  const int c = lane * 8;
  const u16* yr = yb + row * FF;
  const float* xr = x + row * FF;
  float v[8];
  {
    short8 a = *(const short8*)(yr + c);
    float4 b0 = *(const float4*)(xr + c), b1 = *(const float4*)(xr + c + 4);
    v[0] = bf2f((u16)a[0]) + b0.x; v[1] = bf2f((u16)a[1]) + b0.y;
    v[2] = bf2f((u16)a[2]) + b0.z; v[3] = bf2f((u16)a[3]) + b0.w;
    v[4] = bf2f((u16)a[4]) + b1.x; v[5] = bf2f((u16)a[5]) + b1.y;
    v[6] = bf2f((u16)a[6]) + b1.z; v[7] = bf2f((u16)a[7]) + b1.w;
  }
  float s = 0.f, s2 = 0.f;
#pragma unroll
  for (int e = 0; e < 8; ++e) { s += v[e]; s2 += v[e] * v[e]; }
#pragma unroll
  for (int off = 1; off < 64; off <<= 1) {
    s += __shfl_xor(s, off);
    s2 += __shfl_xor(s2, off);
  }
  const float mu = s * (1.f / 512.f);
  const float var = s2 * (1.f / 512.f) - mu * mu;
  const float rs = rsqrtf(var + 1e-5f);
  float4 w0 = *(const float4*)(w + c), w1 = *(const float4*)(w + c + 4);
  float4 b0 = *(const float4*)(bv_ + c), b1 = *(const float4*)(bv_ + c + 4);
  const float wv[8] = {w0.x, w0.y, w0.z, w0.w, w1.x, w1.y, w1.z, w1.w};
  const float bb[8] = {b0.x, b0.y, b0.z, b0.w, b1.x, b1.y, b1.z, b1.w};
  short8 ob;
#pragma unroll
  for (int e = 0; e < 8; ++e)
    ob[e] = (short)f2bf((v[e] - mu) * rs * wv[e] + bb[e]);
  *(short8*)(lg + row * 1024 + c) = ob;
}

// ------------------- gate LN + sigmoid + mix (all bf16 inputs)
__global__ __launch_bounds__(256) void gate_final(
    const u16* __restrict__ gp, const u16* __restrict__ lg,
    const float* __restrict__ w, const float* __restrict__ bv_,
    float* __restrict__ out) {
  const int wave = threadIdx.x >> 6, lane = threadIdx.x & 63;
  const size_t row = (size_t)blockIdx.x * 4 + wave;
  const int c = lane * 8;
  float v[8];
  {
    short8 a = *(const short8*)(gp + row * FF + c);
#pragma unroll
    for (int e = 0; e < 8; ++e) v[e] = bf2f((u16)a[e]);
  }
  float s = 0.f, s2 = 0.f;
#pragma unroll
  for (int e = 0; e < 8; ++e) { s += v[e]; s2 += v[e] * v[e]; }
#pragma unroll
  for (int off = 1; off < 64; off <<= 1) {
    s += __shfl_xor(s, off);
    s2 += __shfl_xor(s2, off);
  }
  const float mu = s * (1.f / 512.f);
  const float var = s2 * (1.f / 512.f) - mu * mu;
  const float rs = rsqrtf(var + 1e-5f);
  float4 w0 = *(const float4*)(w + c), w1 = *(const float4*)(w + c + 4);
  float4 b0 = *(const float4*)(bv_ + c), b1 = *(const float4*)(bv_ + c + 4);
  const float wv[8] = {w0.x, w0.y, w0.z, w0.w, w1.x, w1.y, w1.z, w1.w};
  const float bb[8] = {b0.x, b0.y, b0.z, b0.w, b1.x, b1.y, b1.z, b1.w};
  short8 l8 = *(const short8*)(lg + row * 1024 + c);
  short8 g8 = *(const short8*)(lg + row * 1024 + 512 + c);
  float r[8];
#pragma unroll
  for (int e = 0; e < 8; ++e) {
    const float z = (v[e] - mu) * rs * wv[e] + bb[e];
    const float gt = 1.f / (1.f + exp2f(-1.44269504f * z));
    r[e] = gt * bf2f((u16)l8[e]) + (1.f - gt) * bf2f((u16)g8[e]);
  }
  *(float4*)(out + row * FF + c) = make_float4(r[0], r[1], r[2], r[3]);
  *(float4*)(out + row * FF + c + 4) = make_float4(r[4], r[5], r[6], r[7]);
}

// ---------------------------------------------------------------- launch
extern "C" void kernel_launch(void* const* d_in, const int* in_sizes, int n_in,
                              void* d_out, int out_size, void* d_ws,
                              size_t ws_size, hipStream_t stream) {
  const float* x       = (const float*)d_in[0];
  const float* l_in_w  = (const float*)d_in[1];
  const float* l_in_b  = (const float*)d_in[2];
  const float* l_out_w = (const float*)d_in[3];
  const float* l_out_b = (const float*)d_in[4];
  const float* g_in_w  = (const float*)d_in[5];
  const float* g_in_b  = (const float*)d_in[6];
  const float* g_out_w = (const float*)d_in[7];
  const float* g_out_b = (const float*)d_in[8];
  const float* n1_w    = (const float*)d_in[9];
  const float* n1_b    = (const float*)d_in[10];
  const float* n2_w    = (const float*)d_in[11];
  const float* n2_b    = (const float*)d_in[12];
  const float* gate_w  = (const float*)d_in[13];
  const float* gate_b  = (const float*)d_in[14];
  const float* gln_w   = (const float*)d_in[15];
  const float* gln_b   = (const float*)d_in[16];
  float* out = (float*)d_out;

  const float c1 = 0.12752724808f;  // log2(e)/sqrt(128)

  char* ws = (char*)d_ws;
  u16* x_bf  = (u16*)(ws);                      // 16 MB
  u16* w_qkv = (u16*)(ws + 16777216);           // 3 MB  [l_in_w | g_in_w]
  u16* w_low = (u16*)(ws + 19922944);           // 0.5 MB
  u16* w_gow = (u16*)(ws + 20447232);           // 0.5 MB
  u16* w_gt  = (u16*)(ws + 20971520);           // 1 MB
  u16* qkv2  = (u16*)(ws + 22020096);           // 96 MB fused [local|global] qkv
  u16* vt    = (u16*)(ws + 122683392);          // 16 MB (V^T; reused per branch)
  u16* ato   = (u16*)(ws + 139460608);          // 16 MB attn out (reused)
  u16* prj   = (u16*)(ws + 156237824);          // 16 MB bf16 attn-proj (reused)
  u16* lgbf  = (u16*)(ws + 173015040);          // 32 MB [local|glob] bf16 LN out
  u16* gpre  = (u16*)(ws + 22020096);           // alias qkv2 (free by gate time)

  castk<<<4096, 256, 0, stream>>>(x, x_bf, 8388608);
  castk<<<384, 256, 0, stream>>>(l_in_w, w_qkv, 786432);
  castk<<<384, 256, 0, stream>>>(g_in_w, w_qkv + 786432, 786432);
  castk<<<128, 256, 0, stream>>>(l_out_w, w_low, 262144);
  castk<<<128, 256, 0, stream>>>(g_out_w, w_gow, 262144);
  castk<<<256, 256, 0, stream>>>(gate_w, w_gt, 524288);

  // fused QKV for both branches (Q cols of each branch pre-scaled by c1)
  gemm_bt<<<dim3(128, 24), 256, 0, stream>>>(x_bf, w_qkv, l_in_b, g_in_b, qkv2,
                                             TOK, 3072, 512, 1536, 512, c1);

  // local branch
  transpose_v<<<dim3(32, 32, 2), 256, 0, stream>>>(qkv2, vt);
  attn_local<<<512, 256, 0, stream>>>(qkv2, vt, ato);
  gemm_bt<<<dim3(128, 4), 256, 0, stream>>>(ato, w_low, l_out_b, l_out_b, prj,
                                            TOK, 512, 512, 512, 0, 1.f);
  resid_ln<<<4096, 256, 0, stream>>>(prj, x, n1_w, n1_b, lgbf);

  // global branch
  transpose_v<<<dim3(32, 32, 2), 256, 0, stream>>>(qkv2 + 1536, vt);
  attn_global<<<512, 256, 0, stream>>>(qkv2, vt, ato);
  gemm_bt<<<dim3(128, 4), 256, 0, stream>>>(ato, w_gow, g_out_b, g_out_b, prj,
                                            TOK, 512, 512, 512, 0, 1.f);
  resid_ln<<<4096, 256, 0, stream>>>(prj, x, n2_w, n2_b, lgbf + 512);

  // gate fusion (bf16 in/out)
  gemm_bt<<<dim3(128, 4), 256, 0, stream>>>(lgbf, w_gt, gate_b, gate_b, gpre,
                                            TOK, 512, 1024, 512, 0, 1.f);
  gate_final<<<4096, 256, 0, stream>>>(gpre, lgbf, gln_w, gln_b, out);
}